// Round 3
// baseline (284.811 us; speedup 1.0000x reference)
//
#include <hip/hip_runtime.h>
#include <hip/hip_bf16.h>

#define B_EVENTS 4096
#define L_PTS    524288
#define CIN      16
#define C1       128
#define C2       128
#define C3       64
#define DVEC     32
#define ZDIM     96   // C3 + DVEC
#define M1       256
#define M2       128
#define BN_EPS   1e-5f
#define TPTS     64   // points per pass in phi kernel

typedef __attribute__((ext_vector_type(8))) short bf16x8;
typedef __attribute__((ext_vector_type(4))) float f32x4;

__device__ __forceinline__ ushort f2bf(float x) {
    union { float f; unsigned u; } a; a.f = x;
    unsigned r = (a.u + 0x7fffu + ((a.u >> 16) & 1u)) >> 16;  // RNE
    return (ushort)r;
}

// LDS addressing: point-major [pt][ch] bf16, 16B slots, XOR-swizzled by pt&7
// (bijective within each region; same function used for read and write).
__device__ __forceinline__ int ldsoff(int base, int rowSlots, int c, int sir) {
    int s = c * rowSlots + sir;
    s ^= (c & 7);
    return base + s * 16;
}

// ---------------------------------------------------------------------------
// Kernel 0: exclusive scan of counts -> bounds[B+1]; zero BN stat accumulators
// ---------------------------------------------------------------------------
__global__ __launch_bounds__(1024) void scan_zero_kernel(const int* __restrict__ si,
                                                         int* __restrict__ bounds,
                                                         float* __restrict__ stats) {
    __shared__ int sh[1024];
    const int tid = threadIdx.x;
    const int c0 = si[tid*4+0], c1 = si[tid*4+1], c2 = si[tid*4+2], c3 = si[tid*4+3];
    const int s4 = c0 + c1 + c2 + c3;
    sh[tid] = s4;
    if (tid < 768) stats[tid] = 0.f;   // gsum1[256] gsq1[256] gsum2[128] gsq2[128]
    __syncthreads();
    for (int off = 1; off < 1024; off <<= 1) {
        int add = (tid >= off) ? sh[tid - off] : 0;
        __syncthreads();
        sh[tid] += add;
        __syncthreads();
    }
    const int excl = (tid == 0) ? 0 : sh[tid - 1];
    bounds[tid*4+0] = excl;
    bounds[tid*4+1] = excl + c0;
    bounds[tid*4+2] = excl + c0 + c1;
    bounds[tid*4+3] = excl + c0 + c1 + c2;
    if (tid == 1023) bounds[B_EVENTS] = excl + s4;
}

// ---------------------------------------------------------------------------
// Kernel P: convert weights to bf16 (W1 K-padded 16 -> 32 with zeros)
// ---------------------------------------------------------------------------
__global__ __launch_bounds__(256) void prep_kernel(
    const float* __restrict__ W1, const float* __restrict__ W2, const float* __restrict__ W3,
    ushort* __restrict__ w1p, ushort* __restrict__ w2b, ushort* __restrict__ w3b)
{
    const int tid = blockIdx.x * 256 + threadIdx.x;
    const int nthr = gridDim.x * 256;
    for (int i = tid; i < C1 * 32; i += nthr) {
        const int r = i >> 5, k = i & 31;
        w1p[i] = (k < CIN) ? f2bf(W1[r * CIN + k]) : (ushort)0;
    }
    for (int i = tid; i < C2 * C1; i += nthr) w2b[i] = f2bf(W2[i]);
    for (int i = tid; i < C3 * C2; i += nthr) w3b[i] = f2bf(W3[i]);
}

// ---------------------------------------------------------------------------
// Kernel 1: fused phi (3 layers, bf16 MFMA) + segment mean + concat(x_b)
// block = 256 threads (4 waves, 2x2 wave grid), 1 event per block,
// cnt points processed in passes of TPTS=64.
// LDS: X [64pt][32ch] @0 (4KB), H1 [64pt][128ch] @4096 (16KB),
//      H2 [64pt][128ch] @20480 (16KB). All XOR-swizzled 16B slots.
// ---------------------------------------------------------------------------
__global__ __launch_bounds__(256, 3) void phi_mfma_kernel(
    const float* __restrict__ xa, const float* __restrict__ xb,
    const int* __restrict__ bounds,
    const ushort* __restrict__ w1p, const ushort* __restrict__ w2b, const ushort* __restrict__ w3b,
    const float* __restrict__ b1, const float* __restrict__ b2, const float* __restrict__ b3,
    float* __restrict__ z)
{
    __shared__ __align__(16) char lds[36864];
    __shared__ float msum[C3];

    const int tid  = threadIdx.x;
    const int lane = tid & 63;
    const int wid  = tid >> 6;
    const int wm   = wid >> 1;       // wave row (M half)
    const int wn   = wid & 1;        // wave col (N half: 32 pts)
    const int g4   = lane >> 4;      // 0..3
    const int c16  = lane & 15;      // 0..15

    // ---- preload weight A-fragments into registers ----
    // A layout: lane holds A[row = lane&15][k = (lane>>4)*8 + j], j=0..7
    bf16x8 a1[4], a2[4][4], a3[2][4];
    {
        const int r1 = wm * 64 + c16;
        #pragma unroll
        for (int mf = 0; mf < 4; ++mf)
            a1[mf] = *(const bf16x8*)&w1p[(r1 + mf * 16) * 32 + g4 * 8];
        #pragma unroll
        for (int mf = 0; mf < 4; ++mf)
            #pragma unroll
            for (int kf = 0; kf < 4; ++kf)
                a2[mf][kf] = *(const bf16x8*)&w2b[(r1 + mf * 16) * C1 + kf * 32 + g4 * 8];
        const int r3 = wm * 32 + c16;
        #pragma unroll
        for (int mf = 0; mf < 2; ++mf)
            #pragma unroll
            for (int kf = 0; kf < 4; ++kf)
                a3[mf][kf] = *(const bf16x8*)&w3b[(r3 + mf * 16) * C2 + kf * 32 + g4 * 8];
    }

    const int j     = blockIdx.x;
    const int start = bounds[j];
    const int cnt   = bounds[j + 1] - start;

    // ---- zero X region once (K-pad slots must not hold NaN-pattern garbage) ----
    *(f32x4*)(lds + tid * 16) = f32x4{0.f, 0.f, 0.f, 0.f};
    if (tid < C3) msum[tid] = 0.f;

    const int pt   = tid & 63;       // staging: point owned by this thread
    const int half = tid >> 6;       // staging: channel quad half*4..half*4+3

    for (int p0 = 0; p0 < cnt; p0 += TPTS) {
        __syncthreads();                       // (a) prev-pass reads / zero-init done

        // ---- stage X: 4 coalesced fp32 loads -> pack -> one ds_write_b64 ----
        {
            const int p = p0 + pt;
            union { ushort u[4]; unsigned long long ll; } pk;
            #pragma unroll
            for (int jj = 0; jj < 4; ++jj) {
                const float v = (p < cnt) ? xa[(size_t)(half * 4 + jj) * L_PTS + start + p] : 0.f;
                pk.u[jj] = f2bf(v);
            }
            *(unsigned long long*)(lds + ldsoff(0, 4, pt, half >> 1) + (half & 1) * 8) = pk.ll;
        }
        __syncthreads();                       // (b)

        // ---- layer 1: H1[128ch][64pt] = relu(W1p @ X), K=32 ----
        {
            f32x4 acc[4][2];
            #pragma unroll
            for (int mf = 0; mf < 4; ++mf) {
                const f32x4 bb = *(const f32x4*)&b1[wm * 64 + mf * 16 + g4 * 4];
                acc[mf][0] = bb; acc[mf][1] = bb;
            }
            #pragma unroll
            for (int nf = 0; nf < 2; ++nf) {
                const int c = wn * 32 + nf * 16 + c16;
                const bf16x8 bfrag = *(const bf16x8*)(lds + ldsoff(0, 4, c, g4));
                #pragma unroll
                for (int mf = 0; mf < 4; ++mf)
                    acc[mf][nf] = __builtin_amdgcn_mfma_f32_16x16x32_bf16(a1[mf], bfrag, acc[mf][nf], 0, 0, 0);
            }
            #pragma unroll
            for (int mf = 0; mf < 4; ++mf)
                #pragma unroll
                for (int nf = 0; nf < 2; ++nf) {
                    const int c = wn * 32 + nf * 16 + c16;
                    union { ushort u[4]; unsigned long long ll; } pk;
                    #pragma unroll
                    for (int r = 0; r < 4; ++r) pk.u[r] = f2bf(fmaxf(acc[mf][nf][r], 0.f));
                    const int sir = (wm * 64 + mf * 16) / 8 + (g4 >> 1);
                    *(unsigned long long*)(lds + ldsoff(4096, 16, c, sir) + (g4 & 1) * 8) = pk.ll;
                }
        }
        __syncthreads();                       // (c)

        // ---- layer 2: H2 = relu(W2 @ H1), K=128 ----
        {
            f32x4 acc[4][2];
            #pragma unroll
            for (int mf = 0; mf < 4; ++mf) {
                const f32x4 bb = *(const f32x4*)&b2[wm * 64 + mf * 16 + g4 * 4];
                acc[mf][0] = bb; acc[mf][1] = bb;
            }
            #pragma unroll
            for (int nf = 0; nf < 2; ++nf) {
                const int c = wn * 32 + nf * 16 + c16;
                bf16x8 bk[4];
                #pragma unroll
                for (int kf = 0; kf < 4; ++kf)
                    bk[kf] = *(const bf16x8*)(lds + ldsoff(4096, 16, c, kf * 4 + g4));
                #pragma unroll
                for (int mf = 0; mf < 4; ++mf)
                    #pragma unroll
                    for (int kf = 0; kf < 4; ++kf)
                        acc[mf][nf] = __builtin_amdgcn_mfma_f32_16x16x32_bf16(a2[mf][kf], bk[kf], acc[mf][nf], 0, 0, 0);
            }
            #pragma unroll
            for (int mf = 0; mf < 4; ++mf)
                #pragma unroll
                for (int nf = 0; nf < 2; ++nf) {
                    const int c = wn * 32 + nf * 16 + c16;
                    union { ushort u[4]; unsigned long long ll; } pk;
                    #pragma unroll
                    for (int r = 0; r < 4; ++r) pk.u[r] = f2bf(fmaxf(acc[mf][nf][r], 0.f));
                    const int sir = (wm * 64 + mf * 16) / 8 + (g4 >> 1);
                    *(unsigned long long*)(lds + ldsoff(20480, 16, c, sir) + (g4 & 1) * 8) = pk.ll;
                }
        }
        __syncthreads();                       // (d)

        // ---- layer 3: H3 = relu(W3 @ H2), K=128, M=64; fused masked col-sum ----
        {
            f32x4 acc3[2][2];
            #pragma unroll
            for (int mf = 0; mf < 2; ++mf) {
                const f32x4 bb = *(const f32x4*)&b3[wm * 32 + mf * 16 + g4 * 4];
                acc3[mf][0] = bb; acc3[mf][1] = bb;
            }
            #pragma unroll
            for (int nf = 0; nf < 2; ++nf) {
                const int c = wn * 32 + nf * 16 + c16;
                bf16x8 bk[4];
                #pragma unroll
                for (int kf = 0; kf < 4; ++kf)
                    bk[kf] = *(const bf16x8*)(lds + ldsoff(20480, 16, c, kf * 4 + g4));
                #pragma unroll
                for (int mf = 0; mf < 2; ++mf)
                    #pragma unroll
                    for (int kf = 0; kf < 4; ++kf)
                        acc3[mf][nf] = __builtin_amdgcn_mfma_f32_16x16x32_bf16(a3[mf][kf], bk[kf], acc3[mf][nf], 0, 0, 0);
            }
            float s[2][4];
            #pragma unroll
            for (int mf = 0; mf < 2; ++mf)
                #pragma unroll
                for (int r = 0; r < 4; ++r) s[mf][r] = 0.f;
            #pragma unroll
            for (int nf = 0; nf < 2; ++nf) {
                const int col = p0 + wn * 32 + nf * 16 + c16;
                const bool valid = col < cnt;
                #pragma unroll
                for (int mf = 0; mf < 2; ++mf)
                    #pragma unroll
                    for (int r = 0; r < 4; ++r) {
                        const float v = fmaxf(acc3[mf][nf][r], 0.f);
                        if (valid) s[mf][r] += v;
                    }
            }
            // reduce across the 16 lanes of each g4 group (cols)
            #pragma unroll
            for (int mf = 0; mf < 2; ++mf)
                #pragma unroll
                for (int r = 0; r < 4; ++r) {
                    float v = s[mf][r];
                    #pragma unroll
                    for (int m = 1; m < 16; m <<= 1) v += __shfl_xor(v, m, 64);
                    s[mf][r] = v;
                }
            if (c16 == 0) {
                #pragma unroll
                for (int mf = 0; mf < 2; ++mf)
                    #pragma unroll
                    for (int r = 0; r < 4; ++r)
                        atomicAdd(&msum[wm * 32 + mf * 16 + g4 * 4 + r], s[mf][r]);
            }
        }
    }
    __syncthreads();                           // (e) all atomics done

    if (tid < C3) {
        const float inv = 1.f / (float)max(cnt, 1);
        z[(size_t)j * ZDIM + tid] = msum[tid] * inv;
    } else if (tid < ZDIM) {
        z[(size_t)j * ZDIM + tid] = xb[(size_t)j * DVEC + (tid - C3)];
    }
}

// ---------------------------------------------------------------------------
// Kernel 2: y1 = z @ Wm1.T + bm1   [B,256], plus column sum/sumsq atomics
// ---------------------------------------------------------------------------
__global__ __launch_bounds__(256) void mlp1_kernel(
    const float* __restrict__ z, const float* __restrict__ Wm1, const float* __restrict__ bm1,
    float* __restrict__ y1, float* __restrict__ gsum, float* __restrict__ gsq)
{
    __shared__ float zs[16][ZDIM + 4];
    const int r0 = blockIdx.x * 16;
    const int tid = threadIdx.x;
    for (int i = tid; i < 16 * ZDIM; i += 256) {
        const int r = i / ZDIM, c = i - r * ZDIM;
        zs[r][c] = z[(size_t)(r0 + r) * ZDIM + c];
    }
    __syncthreads();
    const int o = tid;
    float acc[16];
    const float bb = bm1[o];
    #pragma unroll
    for (int r = 0; r < 16; ++r) acc[r] = bb;
    for (int c = 0; c < ZDIM; c += 4) {
        const float4 w = *(const float4*)&Wm1[o * ZDIM + c];
        #pragma unroll
        for (int r = 0; r < 16; ++r) {
            const float4 v = *(const float4*)&zs[r][c];
            acc[r] += w.x*v.x + w.y*v.y + w.z*v.z + w.w*v.w;
        }
    }
    float s = 0.f, sq = 0.f;
    #pragma unroll
    for (int r = 0; r < 16; ++r) {
        y1[(size_t)(r0 + r) * M1 + o] = acc[r];
        s += acc[r]; sq += acc[r] * acc[r];
    }
    atomicAdd(&gsum[o], s);
    atomicAdd(&gsq[o], sq);
}

// ---------------------------------------------------------------------------
// Kernel 3/5: finalize BN -> per-channel scale/shift
// ---------------------------------------------------------------------------
__global__ void bnfin_kernel(const float* __restrict__ gsum, const float* __restrict__ gsq,
                             const float* __restrict__ g, const float* __restrict__ be,
                             float* __restrict__ scale, float* __restrict__ shift, int n)
{
    const int o = blockIdx.x * blockDim.x + threadIdx.x;
    if (o >= n) return;
    const float mu  = gsum[o] * (1.f / B_EVENTS);
    const float var = gsq[o] * (1.f / B_EVENTS) - mu * mu;
    const float rs  = rsqrtf(var + BN_EPS);
    const float sc  = rs * g[o];
    scale[o] = sc;
    shift[o] = be[o] - mu * sc;
}

// ---------------------------------------------------------------------------
// Kernel 4: y2 = relu(bn(y1)) @ Wm2.T + bm2   [B,128], plus stats
// ---------------------------------------------------------------------------
__global__ __launch_bounds__(256) void mlp2_kernel(
    const float* __restrict__ y1, const float* __restrict__ scale1, const float* __restrict__ shift1,
    const float* __restrict__ Wm2, const float* __restrict__ bm2,
    float* __restrict__ y2, float* __restrict__ gsum, float* __restrict__ gsq)
{
    __shared__ float zs[16][M1 + 4];
    const int r0 = blockIdx.x * 16;
    const int tid = threadIdx.x;
    for (int i = tid; i < 16 * M1; i += 256) {
        const int r = i >> 8, c = i & (M1 - 1);
        const float v = y1[(size_t)(r0 + r) * M1 + c];
        zs[r][c] = fmaxf(v * scale1[c] + shift1[c], 0.f);
    }
    __syncthreads();
    const int o = tid & 127;
    const int h = tid >> 7;
    float acc[8];
    const float bb = bm2[o];
    #pragma unroll
    for (int r = 0; r < 8; ++r) acc[r] = bb;
    for (int c = 0; c < M1; c += 4) {
        const float4 w = *(const float4*)&Wm2[o * M1 + c];
        #pragma unroll
        for (int r = 0; r < 8; ++r) {
            const float4 v = *(const float4*)&zs[h * 8 + r][c];
            acc[r] += w.x*v.x + w.y*v.y + w.z*v.z + w.w*v.w;
        }
    }
    float s = 0.f, sq = 0.f;
    #pragma unroll
    for (int r = 0; r < 8; ++r) {
        y2[(size_t)(r0 + h * 8 + r) * M2 + o] = acc[r];
        s += acc[r]; sq += acc[r] * acc[r];
    }
    atomicAdd(&gsum[o], s);
    atomicAdd(&gsq[o], sq);
}

// ---------------------------------------------------------------------------
// Kernel 6: out = sigmoid(relu(bn(y2)) @ Wm3.T + bm3)   [B,1]
// ---------------------------------------------------------------------------
__global__ __launch_bounds__(256) void final_kernel(
    const float* __restrict__ y2, const float* __restrict__ scale2, const float* __restrict__ shift2,
    const float* __restrict__ Wm3, const float* __restrict__ bm3,
    float* __restrict__ out)
{
    const int tid = threadIdx.x;
    const int w = tid >> 6, l = tid & 63;
    const int r = blockIdx.x * 4 + w;
    const float e0 = fmaxf(y2[(size_t)r * M2 + l]      * scale2[l]      + shift2[l],      0.f);
    const float e1 = fmaxf(y2[(size_t)r * M2 + 64 + l] * scale2[64 + l] + shift2[64 + l], 0.f);
    float a = e0 * Wm3[l] + e1 * Wm3[64 + l];
    #pragma unroll
    for (int off = 32; off >= 1; off >>= 1) a += __shfl_down(a, off, 64);
    if (l == 0) out[r] = 1.f / (1.f + expf(-(a + bm3[0])));
}

// ---------------------------------------------------------------------------
extern "C" void kernel_launch(void* const* d_in, const int* in_sizes, int n_in,
                              void* d_out, int out_size, void* d_ws, size_t ws_size,
                              hipStream_t stream) {
    const float* xa  = (const float*)d_in[0];
    const float* xb  = (const float*)d_in[1];
    const int*   si  = (const int*)  d_in[2];
    const float* W1  = (const float*)d_in[3];
    const float* b1  = (const float*)d_in[4];
    const float* W2  = (const float*)d_in[5];
    const float* b2  = (const float*)d_in[6];
    const float* W3  = (const float*)d_in[7];
    const float* b3  = (const float*)d_in[8];
    const float* Wm1 = (const float*)d_in[9];
    const float* bm1 = (const float*)d_in[10];
    const float* g1  = (const float*)d_in[11];
    const float* be1 = (const float*)d_in[12];
    const float* Wm2 = (const float*)d_in[13];
    const float* bm2 = (const float*)d_in[14];
    const float* g2  = (const float*)d_in[15];
    const float* be2 = (const float*)d_in[16];
    const float* Wm3 = (const float*)d_in[17];
    const float* bm3 = (const float*)d_in[18];
    float* out = (float*)d_out;

    char* ws = (char*)d_ws;
    size_t off = 0;
    auto alloc = [&](size_t bytes) -> void* {
        void* p = ws + off;
        off = (off + bytes + 255) & ~(size_t)255;
        return p;
    };
    int*    bounds = (int*)   alloc((B_EVENTS + 1) * sizeof(int));
    float*  stats  = (float*) alloc(768 * sizeof(float));
    float*  z      = (float*) alloc((size_t)B_EVENTS * ZDIM * sizeof(float));
    float*  y1     = (float*) alloc((size_t)B_EVENTS * M1 * sizeof(float));
    float*  y2     = (float*) alloc((size_t)B_EVENTS * M2 * sizeof(float));
    float*  scale1 = (float*) alloc(M1 * sizeof(float));
    float*  shift1 = (float*) alloc(M1 * sizeof(float));
    float*  scale2 = (float*) alloc(M2 * sizeof(float));
    float*  shift2 = (float*) alloc(M2 * sizeof(float));
    ushort* w1p    = (ushort*)alloc(C1 * 32 * sizeof(ushort));
    ushort* w2b    = (ushort*)alloc(C2 * C1 * sizeof(ushort));
    ushort* w3b    = (ushort*)alloc(C3 * C2 * sizeof(ushort));
    float* gsum1 = stats;
    float* gsq1  = stats + 256;
    float* gsum2 = stats + 512;
    float* gsq2  = stats + 640;

    hipLaunchKernelGGL(scan_zero_kernel, dim3(1), dim3(1024), 0, stream, si, bounds, stats);
    hipLaunchKernelGGL(prep_kernel, dim3(16), dim3(256), 0, stream, W1, W2, W3, w1p, w2b, w3b);
    hipLaunchKernelGGL(phi_mfma_kernel, dim3(B_EVENTS), dim3(256), 0, stream,
                       xa, xb, bounds, w1p, w2b, w3b, b1, b2, b3, z);
    hipLaunchKernelGGL(mlp1_kernel, dim3(B_EVENTS / 16), dim3(256), 0, stream,
                       z, Wm1, bm1, y1, gsum1, gsq1);
    hipLaunchKernelGGL(bnfin_kernel, dim3(1), dim3(256), 0, stream,
                       gsum1, gsq1, g1, be1, scale1, shift1, M1);
    hipLaunchKernelGGL(mlp2_kernel, dim3(B_EVENTS / 16), dim3(256), 0, stream,
                       y1, scale1, shift1, Wm2, bm2, y2, gsum2, gsq2);
    hipLaunchKernelGGL(bnfin_kernel, dim3(1), dim3(128), 0, stream,
                       gsum2, gsq2, g2, be2, scale2, shift2, M2);
    hipLaunchKernelGGL(final_kernel, dim3(B_EVENTS / 4), dim3(256), 0, stream,
                       y2, scale2, shift2, Wm3, bm3, out);
}

// Round 4
// 150.051 us; speedup vs baseline: 1.8981x; 1.8981x over previous
//
#include <hip/hip_runtime.h>
#include <hip/hip_bf16.h>

#define B_EVENTS 4096
#define L_PTS    524288
#define CIN      16
#define C1       128
#define C2       128
#define C3       64
#define DVEC     32
#define ZDIM     96   // C3 + DVEC
#define M1       256
#define M2       128
#define BN_EPS   1e-5f
#define TPTS     64   // points per pass in phi kernel

typedef __attribute__((ext_vector_type(8))) short bf16x8;
typedef __attribute__((ext_vector_type(4))) float f32x4;

__device__ __forceinline__ ushort f2bf(float x) {
    union { float f; unsigned u; } a; a.f = x;
    unsigned r = (a.u + 0x7fffu + ((a.u >> 16) & 1u)) >> 16;  // RNE
    return (ushort)r;
}

// LDS addressing: point-major [pt][ch] bf16, 16B slots, XOR-swizzled by pt&7
// (bijective within each region; same function used for read and write).
__device__ __forceinline__ int ldsoff(int base, int rowSlots, int c, int sir) {
    int s = c * rowSlots + sir;
    s ^= (c & 7);
    return base + s * 16;
}

// ---------------------------------------------------------------------------
// Kernel 0: exclusive scan of counts -> bounds[B+1]; zero BN stat accumulators
// ---------------------------------------------------------------------------
__global__ __launch_bounds__(1024) void scan_zero_kernel(const int* __restrict__ si,
                                                         int* __restrict__ bounds,
                                                         float* __restrict__ stats) {
    __shared__ int sh[1024];
    const int tid = threadIdx.x;
    const int c0 = si[tid*4+0], c1 = si[tid*4+1], c2 = si[tid*4+2], c3 = si[tid*4+3];
    const int s4 = c0 + c1 + c2 + c3;
    sh[tid] = s4;
    if (tid < 768) stats[tid] = 0.f;   // gsum1[256] gsq1[256] gsum2[128] gsq2[128]
    __syncthreads();
    for (int off = 1; off < 1024; off <<= 1) {
        int add = (tid >= off) ? sh[tid - off] : 0;
        __syncthreads();
        sh[tid] += add;
        __syncthreads();
    }
    const int excl = (tid == 0) ? 0 : sh[tid - 1];
    bounds[tid*4+0] = excl;
    bounds[tid*4+1] = excl + c0;
    bounds[tid*4+2] = excl + c0 + c1;
    bounds[tid*4+3] = excl + c0 + c1 + c2;
    if (tid == 1023) bounds[B_EVENTS] = excl + s4;
}

// ---------------------------------------------------------------------------
// Kernel P: convert weights to bf16 (W1 K-padded 16 -> 32 with zeros)
// ---------------------------------------------------------------------------
__global__ __launch_bounds__(256) void prep_kernel(
    const float* __restrict__ W1, const float* __restrict__ W2, const float* __restrict__ W3,
    ushort* __restrict__ w1p, ushort* __restrict__ w2b, ushort* __restrict__ w3b)
{
    const int tid = blockIdx.x * 256 + threadIdx.x;
    const int nthr = gridDim.x * 256;
    for (int i = tid; i < C1 * 32; i += nthr) {
        const int r = i >> 5, k = i & 31;
        w1p[i] = (k < CIN) ? f2bf(W1[r * CIN + k]) : (ushort)0;
    }
    for (int i = tid; i < C2 * C1; i += nthr) w2b[i] = f2bf(W2[i]);
    for (int i = tid; i < C3 * C2; i += nthr) w3b[i] = f2bf(W3[i]);
}

// ---------------------------------------------------------------------------
// Kernel 1: fused phi (3 layers, bf16 MFMA) + segment mean + concat(x_b)
// block = 256 threads (4 waves, 2x2 wave grid), 1 event per block,
// cnt points processed in passes of TPTS=64.
// LDS: X [64pt][32ch] @0 (4KB), H1 [64pt][128ch] @4096 (16KB),
//      H2 [64pt][128ch] @20480 (16KB). All XOR-swizzled 16B slots.
// NOTE: min-waves bound is 2 (VGPR cap 256): the weight fragments alone need
// 112 VGPRs; (256,3) capped at 170->spilled them to scratch (423MB WRITE_SIZE,
// round-3 regression).
// ---------------------------------------------------------------------------
__global__ __launch_bounds__(256, 2) void phi_mfma_kernel(
    const float* __restrict__ xa, const float* __restrict__ xb,
    const int* __restrict__ bounds,
    const ushort* __restrict__ w1p, const ushort* __restrict__ w2b, const ushort* __restrict__ w3b,
    const float* __restrict__ b1, const float* __restrict__ b2, const float* __restrict__ b3,
    float* __restrict__ z)
{
    __shared__ __align__(16) char lds[36864];
    __shared__ float msum[C3];

    const int tid  = threadIdx.x;
    const int lane = tid & 63;
    const int wid  = tid >> 6;
    const int wm   = wid >> 1;       // wave row (M half)
    const int wn   = wid & 1;        // wave col (N half: 32 pts)
    const int g4   = lane >> 4;      // 0..3
    const int c16  = lane & 15;      // 0..15

    // ---- preload weight A-fragments into registers ----
    // A layout: lane holds A[row = lane&15][k = (lane>>4)*8 + j], j=0..7
    bf16x8 a1[4], a2[4][4], a3[2][4];
    {
        const int r1 = wm * 64 + c16;
        #pragma unroll
        for (int mf = 0; mf < 4; ++mf)
            a1[mf] = *(const bf16x8*)&w1p[(r1 + mf * 16) * 32 + g4 * 8];
        #pragma unroll
        for (int mf = 0; mf < 4; ++mf)
            #pragma unroll
            for (int kf = 0; kf < 4; ++kf)
                a2[mf][kf] = *(const bf16x8*)&w2b[(r1 + mf * 16) * C1 + kf * 32 + g4 * 8];
        const int r3 = wm * 32 + c16;
        #pragma unroll
        for (int mf = 0; mf < 2; ++mf)
            #pragma unroll
            for (int kf = 0; kf < 4; ++kf)
                a3[mf][kf] = *(const bf16x8*)&w3b[(r3 + mf * 16) * C2 + kf * 32 + g4 * 8];
    }

    const int j     = blockIdx.x;
    const int start = bounds[j];
    const int cnt   = bounds[j + 1] - start;

    // ---- zero X region once (K-pad slots must not hold NaN-pattern garbage) ----
    *(f32x4*)(lds + tid * 16) = f32x4{0.f, 0.f, 0.f, 0.f};
    if (tid < C3) msum[tid] = 0.f;

    const int pt   = tid & 63;       // staging: point owned by this thread
    const int half = tid >> 6;       // staging: channel quad half*4..half*4+3

    for (int p0 = 0; p0 < cnt; p0 += TPTS) {
        __syncthreads();                       // (a) prev-pass reads / zero-init done

        // ---- stage X: 4 coalesced fp32 loads -> pack -> one ds_write_b64 ----
        {
            const int p = p0 + pt;
            union { ushort u[4]; unsigned long long ll; } pk;
            #pragma unroll
            for (int jj = 0; jj < 4; ++jj) {
                const float v = (p < cnt) ? xa[(size_t)(half * 4 + jj) * L_PTS + start + p] : 0.f;
                pk.u[jj] = f2bf(v);
            }
            *(unsigned long long*)(lds + ldsoff(0, 4, pt, half >> 1) + (half & 1) * 8) = pk.ll;
        }
        __syncthreads();                       // (b)

        // ---- layer 1: H1[128ch][64pt] = relu(W1p @ X), K=32 ----
        {
            f32x4 acc[4][2];
            #pragma unroll
            for (int mf = 0; mf < 4; ++mf) {
                const f32x4 bb = *(const f32x4*)&b1[wm * 64 + mf * 16 + g4 * 4];
                acc[mf][0] = bb; acc[mf][1] = bb;
            }
            #pragma unroll
            for (int nf = 0; nf < 2; ++nf) {
                const int c = wn * 32 + nf * 16 + c16;
                const bf16x8 bfrag = *(const bf16x8*)(lds + ldsoff(0, 4, c, g4));
                #pragma unroll
                for (int mf = 0; mf < 4; ++mf)
                    acc[mf][nf] = __builtin_amdgcn_mfma_f32_16x16x32_bf16(a1[mf], bfrag, acc[mf][nf], 0, 0, 0);
            }
            #pragma unroll
            for (int mf = 0; mf < 4; ++mf)
                #pragma unroll
                for (int nf = 0; nf < 2; ++nf) {
                    const int c = wn * 32 + nf * 16 + c16;
                    union { ushort u[4]; unsigned long long ll; } pk;
                    #pragma unroll
                    for (int r = 0; r < 4; ++r) pk.u[r] = f2bf(fmaxf(acc[mf][nf][r], 0.f));
                    const int sir = (wm * 64 + mf * 16) / 8 + (g4 >> 1);
                    *(unsigned long long*)(lds + ldsoff(4096, 16, c, sir) + (g4 & 1) * 8) = pk.ll;
                }
        }
        __syncthreads();                       // (c)

        // ---- layer 2: H2 = relu(W2 @ H1), K=128 ----
        {
            f32x4 acc[4][2];
            #pragma unroll
            for (int mf = 0; mf < 4; ++mf) {
                const f32x4 bb = *(const f32x4*)&b2[wm * 64 + mf * 16 + g4 * 4];
                acc[mf][0] = bb; acc[mf][1] = bb;
            }
            #pragma unroll
            for (int nf = 0; nf < 2; ++nf) {
                const int c = wn * 32 + nf * 16 + c16;
                bf16x8 bk[4];
                #pragma unroll
                for (int kf = 0; kf < 4; ++kf)
                    bk[kf] = *(const bf16x8*)(lds + ldsoff(4096, 16, c, kf * 4 + g4));
                #pragma unroll
                for (int mf = 0; mf < 4; ++mf)
                    #pragma unroll
                    for (int kf = 0; kf < 4; ++kf)
                        acc[mf][nf] = __builtin_amdgcn_mfma_f32_16x16x32_bf16(a2[mf][kf], bk[kf], acc[mf][nf], 0, 0, 0);
            }
            #pragma unroll
            for (int mf = 0; mf < 4; ++mf)
                #pragma unroll
                for (int nf = 0; nf < 2; ++nf) {
                    const int c = wn * 32 + nf * 16 + c16;
                    union { ushort u[4]; unsigned long long ll; } pk;
                    #pragma unroll
                    for (int r = 0; r < 4; ++r) pk.u[r] = f2bf(fmaxf(acc[mf][nf][r], 0.f));
                    const int sir = (wm * 64 + mf * 16) / 8 + (g4 >> 1);
                    *(unsigned long long*)(lds + ldsoff(20480, 16, c, sir) + (g4 & 1) * 8) = pk.ll;
                }
        }
        __syncthreads();                       // (d)

        // ---- layer 3: H3 = relu(W3 @ H2), K=128, M=64; fused masked col-sum ----
        {
            f32x4 acc3[2][2];
            #pragma unroll
            for (int mf = 0; mf < 2; ++mf) {
                const f32x4 bb = *(const f32x4*)&b3[wm * 32 + mf * 16 + g4 * 4];
                acc3[mf][0] = bb; acc3[mf][1] = bb;
            }
            #pragma unroll
            for (int nf = 0; nf < 2; ++nf) {
                const int c = wn * 32 + nf * 16 + c16;
                bf16x8 bk[4];
                #pragma unroll
                for (int kf = 0; kf < 4; ++kf)
                    bk[kf] = *(const bf16x8*)(lds + ldsoff(20480, 16, c, kf * 4 + g4));
                #pragma unroll
                for (int mf = 0; mf < 2; ++mf)
                    #pragma unroll
                    for (int kf = 0; kf < 4; ++kf)
                        acc3[mf][nf] = __builtin_amdgcn_mfma_f32_16x16x32_bf16(a3[mf][kf], bk[kf], acc3[mf][nf], 0, 0, 0);
            }
            float s[2][4];
            #pragma unroll
            for (int mf = 0; mf < 2; ++mf)
                #pragma unroll
                for (int r = 0; r < 4; ++r) s[mf][r] = 0.f;
            #pragma unroll
            for (int nf = 0; nf < 2; ++nf) {
                const int col = p0 + wn * 32 + nf * 16 + c16;
                const bool valid = col < cnt;
                #pragma unroll
                for (int mf = 0; mf < 2; ++mf)
                    #pragma unroll
                    for (int r = 0; r < 4; ++r) {
                        const float v = fmaxf(acc3[mf][nf][r], 0.f);
                        if (valid) s[mf][r] += v;
                    }
            }
            // reduce across the 16 lanes of each g4 group (cols)
            #pragma unroll
            for (int mf = 0; mf < 2; ++mf)
                #pragma unroll
                for (int r = 0; r < 4; ++r) {
                    float v = s[mf][r];
                    #pragma unroll
                    for (int m = 1; m < 16; m <<= 1) v += __shfl_xor(v, m, 64);
                    s[mf][r] = v;
                }
            if (c16 == 0) {
                #pragma unroll
                for (int mf = 0; mf < 2; ++mf)
                    #pragma unroll
                    for (int r = 0; r < 4; ++r)
                        atomicAdd(&msum[wm * 32 + mf * 16 + g4 * 4 + r], s[mf][r]);
            }
        }
    }
    __syncthreads();                           // (e) all atomics done

    if (tid < C3) {
        const float inv = 1.f / (float)max(cnt, 1);
        z[(size_t)j * ZDIM + tid] = msum[tid] * inv;
    } else if (tid < ZDIM) {
        z[(size_t)j * ZDIM + tid] = xb[(size_t)j * DVEC + (tid - C3)];
    }
}

// ---------------------------------------------------------------------------
// Kernel 2: y1 = z @ Wm1.T + bm1   [B,256], plus column sum/sumsq atomics
// ---------------------------------------------------------------------------
__global__ __launch_bounds__(256) void mlp1_kernel(
    const float* __restrict__ z, const float* __restrict__ Wm1, const float* __restrict__ bm1,
    float* __restrict__ y1, float* __restrict__ gsum, float* __restrict__ gsq)
{
    __shared__ float zs[16][ZDIM + 4];
    const int r0 = blockIdx.x * 16;
    const int tid = threadIdx.x;
    for (int i = tid; i < 16 * ZDIM; i += 256) {
        const int r = i / ZDIM, c = i - r * ZDIM;
        zs[r][c] = z[(size_t)(r0 + r) * ZDIM + c];
    }
    __syncthreads();
    const int o = tid;
    float acc[16];
    const float bb = bm1[o];
    #pragma unroll
    for (int r = 0; r < 16; ++r) acc[r] = bb;
    for (int c = 0; c < ZDIM; c += 4) {
        const float4 w = *(const float4*)&Wm1[o * ZDIM + c];
        #pragma unroll
        for (int r = 0; r < 16; ++r) {
            const float4 v = *(const float4*)&zs[r][c];
            acc[r] += w.x*v.x + w.y*v.y + w.z*v.z + w.w*v.w;
        }
    }
    float s = 0.f, sq = 0.f;
    #pragma unroll
    for (int r = 0; r < 16; ++r) {
        y1[(size_t)(r0 + r) * M1 + o] = acc[r];
        s += acc[r]; sq += acc[r] * acc[r];
    }
    atomicAdd(&gsum[o], s);
    atomicAdd(&gsq[o], sq);
}

// ---------------------------------------------------------------------------
// Kernel 3/5: finalize BN -> per-channel scale/shift
// ---------------------------------------------------------------------------
__global__ void bnfin_kernel(const float* __restrict__ gsum, const float* __restrict__ gsq,
                             const float* __restrict__ g, const float* __restrict__ be,
                             float* __restrict__ scale, float* __restrict__ shift, int n)
{
    const int o = blockIdx.x * blockDim.x + threadIdx.x;
    if (o >= n) return;
    const float mu  = gsum[o] * (1.f / B_EVENTS);
    const float var = gsq[o] * (1.f / B_EVENTS) - mu * mu;
    const float rs  = rsqrtf(var + BN_EPS);
    const float sc  = rs * g[o];
    scale[o] = sc;
    shift[o] = be[o] - mu * sc;
}

// ---------------------------------------------------------------------------
// Kernel 4: y2 = relu(bn(y1)) @ Wm2.T + bm2   [B,128], plus stats
// ---------------------------------------------------------------------------
__global__ __launch_bounds__(256) void mlp2_kernel(
    const float* __restrict__ y1, const float* __restrict__ scale1, const float* __restrict__ shift1,
    const float* __restrict__ Wm2, const float* __restrict__ bm2,
    float* __restrict__ y2, float* __restrict__ gsum, float* __restrict__ gsq)
{
    __shared__ float zs[16][M1 + 4];
    const int r0 = blockIdx.x * 16;
    const int tid = threadIdx.x;
    for (int i = tid; i < 16 * M1; i += 256) {
        const int r = i >> 8, c = i & (M1 - 1);
        const float v = y1[(size_t)(r0 + r) * M1 + c];
        zs[r][c] = fmaxf(v * scale1[c] + shift1[c], 0.f);
    }
    __syncthreads();
    const int o = tid & 127;
    const int h = tid >> 7;
    float acc[8];
    const float bb = bm2[o];
    #pragma unroll
    for (int r = 0; r < 8; ++r) acc[r] = bb;
    for (int c = 0; c < M1; c += 4) {
        const float4 w = *(const float4*)&Wm2[o * M1 + c];
        #pragma unroll
        for (int r = 0; r < 8; ++r) {
            const float4 v = *(const float4*)&zs[h * 8 + r][c];
            acc[r] += w.x*v.x + w.y*v.y + w.z*v.z + w.w*v.w;
        }
    }
    float s = 0.f, sq = 0.f;
    #pragma unroll
    for (int r = 0; r < 8; ++r) {
        y2[(size_t)(r0 + h * 8 + r) * M2 + o] = acc[r];
        s += acc[r]; sq += acc[r] * acc[r];
    }
    atomicAdd(&gsum[o], s);
    atomicAdd(&gsq[o], sq);
}

// ---------------------------------------------------------------------------
// Kernel 6: out = sigmoid(relu(bn(y2)) @ Wm3.T + bm3)   [B,1]
// ---------------------------------------------------------------------------
__global__ __launch_bounds__(256) void final_kernel(
    const float* __restrict__ y2, const float* __restrict__ scale2, const float* __restrict__ shift2,
    const float* __restrict__ Wm3, const float* __restrict__ bm3,
    float* __restrict__ out)
{
    const int tid = threadIdx.x;
    const int w = tid >> 6, l = tid & 63;
    const int r = blockIdx.x * 4 + w;
    const float e0 = fmaxf(y2[(size_t)r * M2 + l]      * scale2[l]      + shift2[l],      0.f);
    const float e1 = fmaxf(y2[(size_t)r * M2 + 64 + l] * scale2[64 + l] + shift2[64 + l], 0.f);
    float a = e0 * Wm3[l] + e1 * Wm3[64 + l];
    #pragma unroll
    for (int off = 32; off >= 1; off >>= 1) a += __shfl_down(a, off, 64);
    if (l == 0) out[r] = 1.f / (1.f + expf(-(a + bm3[0])));
}

// ---------------------------------------------------------------------------
extern "C" void kernel_launch(void* const* d_in, const int* in_sizes, int n_in,
                              void* d_out, int out_size, void* d_ws, size_t ws_size,
                              hipStream_t stream) {
    const float* xa  = (const float*)d_in[0];
    const float* xb  = (const float*)d_in[1];
    const int*   si  = (const int*)  d_in[2];
    const float* W1  = (const float*)d_in[3];
    const float* b1  = (const float*)d_in[4];
    const float* W2  = (const float*)d_in[5];
    const float* b2  = (const float*)d_in[6];
    const float* W3  = (const float*)d_in[7];
    const float* b3  = (const float*)d_in[8];
    const float* Wm1 = (const float*)d_in[9];
    const float* bm1 = (const float*)d_in[10];
    const float* g1  = (const float*)d_in[11];
    const float* be1 = (const float*)d_in[12];
    const float* Wm2 = (const float*)d_in[13];
    const float* bm2 = (const float*)d_in[14];
    const float* g2  = (const float*)d_in[15];
    const float* be2 = (const float*)d_in[16];
    const float* Wm3 = (const float*)d_in[17];
    const float* bm3 = (const float*)d_in[18];
    float* out = (float*)d_out;

    char* ws = (char*)d_ws;
    size_t off = 0;
    auto alloc = [&](size_t bytes) -> void* {
        void* p = ws + off;
        off = (off + bytes + 255) & ~(size_t)255;
        return p;
    };
    int*    bounds = (int*)   alloc((B_EVENTS + 1) * sizeof(int));
    float*  stats  = (float*) alloc(768 * sizeof(float));
    float*  z      = (float*) alloc((size_t)B_EVENTS * ZDIM * sizeof(float));
    float*  y1     = (float*) alloc((size_t)B_EVENTS * M1 * sizeof(float));
    float*  y2     = (float*) alloc((size_t)B_EVENTS * M2 * sizeof(float));
    float*  scale1 = (float*) alloc(M1 * sizeof(float));
    float*  shift1 = (float*) alloc(M1 * sizeof(float));
    float*  scale2 = (float*) alloc(M2 * sizeof(float));
    float*  shift2 = (float*) alloc(M2 * sizeof(float));
    ushort* w1p    = (ushort*)alloc(C1 * 32 * sizeof(ushort));
    ushort* w2b    = (ushort*)alloc(C2 * C1 * sizeof(ushort));
    ushort* w3b    = (ushort*)alloc(C3 * C2 * sizeof(ushort));
    float* gsum1 = stats;
    float* gsq1  = stats + 256;
    float* gsum2 = stats + 512;
    float* gsq2  = stats + 640;

    hipLaunchKernelGGL(scan_zero_kernel, dim3(1), dim3(1024), 0, stream, si, bounds, stats);
    hipLaunchKernelGGL(prep_kernel, dim3(16), dim3(256), 0, stream, W1, W2, W3, w1p, w2b, w3b);
    hipLaunchKernelGGL(phi_mfma_kernel, dim3(B_EVENTS), dim3(256), 0, stream,
                       xa, xb, bounds, w1p, w2b, w3b, b1, b2, b3, z);
    hipLaunchKernelGGL(mlp1_kernel, dim3(B_EVENTS / 16), dim3(256), 0, stream,
                       z, Wm1, bm1, y1, gsum1, gsq1);
    hipLaunchKernelGGL(bnfin_kernel, dim3(1), dim3(256), 0, stream,
                       gsum1, gsq1, g1, be1, scale1, shift1, M1);
    hipLaunchKernelGGL(mlp2_kernel, dim3(B_EVENTS / 16), dim3(256), 0, stream,
                       y1, scale1, shift1, Wm2, bm2, y2, gsum2, gsq2);
    hipLaunchKernelGGL(bnfin_kernel, dim3(1), dim3(128), 0, stream,
                       gsum2, gsq2, g2, be2, scale2, shift2, M2);
    hipLaunchKernelGGL(final_kernel, dim3(B_EVENTS / 4), dim3(256), 0, stream,
                       y2, scale2, shift2, Wm3, bm3, out);
}

// Round 5
// 132.755 us; speedup vs baseline: 2.1454x; 1.1303x over previous
//
#include <hip/hip_runtime.h>
#include <hip/hip_bf16.h>

#define B_EVENTS 4096
#define L_PTS    524288
#define CIN      16
#define C1       128
#define C2       128
#define C3       64
#define DVEC     32
#define ZDIM     96   // C3 + DVEC
#define M1       256
#define M2       128
#define BN_EPS   1e-5f
#define TPTS     64   // points per pass in phi kernel
#define EPB      4    // events per block (amortize weight-fragment loads)

typedef __attribute__((ext_vector_type(8))) short bf16x8;
typedef __attribute__((ext_vector_type(4))) float f32x4;

__device__ __forceinline__ ushort f2bf(float x) {
    union { float f; unsigned u; } a; a.f = x;
    unsigned r = (a.u + 0x7fffu + ((a.u >> 16) & 1u)) >> 16;  // RNE
    return (ushort)r;
}

// HW packed f32->bf16 (RNE), 2 values per instruction. No builtin on gfx950.
__device__ __forceinline__ unsigned cvtpk(float lo, float hi) {
    unsigned r;
    asm("v_cvt_pk_bf16_f32 %0, %1, %2" : "=v"(r) : "v"(lo), "v"(hi));
    return r;
}

// relu + pack 4 f32 -> 4 bf16 (8B)
__device__ __forceinline__ unsigned long long pack4relu(f32x4 a) {
    union { unsigned u[2]; unsigned long long ll; } pk;
    pk.u[0] = cvtpk(fmaxf(a[0], 0.f), fmaxf(a[1], 0.f));
    pk.u[1] = cvtpk(fmaxf(a[2], 0.f), fmaxf(a[3], 0.f));
    return pk.ll;
}

// LDS addressing: point-major [pt][ch] bf16, 16B slots, XOR-swizzled by pt&7
// (bijective within each region; same function used for read and write).
__device__ __forceinline__ int ldsoff(int base, int rowSlots, int c, int sir) {
    int s = c * rowSlots + sir;
    s ^= (c & 7);
    return base + s * 16;
}

// ---------------------------------------------------------------------------
// Kernel 0: exclusive scan of counts -> bounds[B+1]; zero BN stat accumulators
// ---------------------------------------------------------------------------
__global__ __launch_bounds__(1024) void scan_zero_kernel(const int* __restrict__ si,
                                                         int* __restrict__ bounds,
                                                         float* __restrict__ stats) {
    __shared__ int sh[1024];
    const int tid = threadIdx.x;
    const int c0 = si[tid*4+0], c1 = si[tid*4+1], c2 = si[tid*4+2], c3 = si[tid*4+3];
    const int s4 = c0 + c1 + c2 + c3;
    sh[tid] = s4;
    if (tid < 768) stats[tid] = 0.f;   // gsum1[256] gsq1[256] gsum2[128] gsq2[128]
    __syncthreads();
    for (int off = 1; off < 1024; off <<= 1) {
        int add = (tid >= off) ? sh[tid - off] : 0;
        __syncthreads();
        sh[tid] += add;
        __syncthreads();
    }
    const int excl = (tid == 0) ? 0 : sh[tid - 1];
    bounds[tid*4+0] = excl;
    bounds[tid*4+1] = excl + c0;
    bounds[tid*4+2] = excl + c0 + c1;
    bounds[tid*4+3] = excl + c0 + c1 + c2;
    if (tid == 1023) bounds[B_EVENTS] = excl + s4;
}

// ---------------------------------------------------------------------------
// Kernel P: convert weights to bf16 (W1 K-padded 16 -> 32 with zeros)
// ---------------------------------------------------------------------------
__global__ __launch_bounds__(256) void prep_kernel(
    const float* __restrict__ W1, const float* __restrict__ W2, const float* __restrict__ W3,
    ushort* __restrict__ w1p, ushort* __restrict__ w2b, ushort* __restrict__ w3b)
{
    const int tid = blockIdx.x * 256 + threadIdx.x;
    const int nthr = gridDim.x * 256;
    for (int i = tid; i < C1 * 32; i += nthr) {
        const int r = i >> 5, k = i & 31;
        w1p[i] = (k < CIN) ? f2bf(W1[r * CIN + k]) : (ushort)0;
    }
    for (int i = tid; i < C2 * C1; i += nthr) w2b[i] = f2bf(W2[i]);
    for (int i = tid; i < C3 * C2; i += nthr) w3b[i] = f2bf(W3[i]);
}

// ---------------------------------------------------------------------------
// Kernel 1: fused phi (3 layers, bf16 MFMA) + segment mean + concat(x_b)
// block = 256 threads (4 waves, 2x2 wave grid), EPB events per block,
// per event cnt points in passes of TPTS=64.
// LDS: X [64pt][32ch] @0 (4KB, single buffer), H1 @4096 (16KB), H2 @20480 (16KB).
// Pipeline per pass (3 barriers): [issue next-X global loads] L1 |bar| L2 |bar|
// [ds_write next-X] L3+msum |bar|.  next-X ds_write is legal after bar2 since
// L1 (the only X reader) completed at bar1; HBM latency hides under L1+L2.
// NOTE: min-waves bound is 2 (VGPR cap 256): weight fragments alone need 112
// VGPRs; (256,3) capped at 170 -> spilled to scratch (423MB WRITE_SIZE, r3).
// ---------------------------------------------------------------------------
__global__ __launch_bounds__(256, 2) void phi_mfma_kernel(
    const float* __restrict__ xa, const float* __restrict__ xb,
    const int* __restrict__ bounds,
    const ushort* __restrict__ w1p, const ushort* __restrict__ w2b, const ushort* __restrict__ w3b,
    const float* __restrict__ b1, const float* __restrict__ b2, const float* __restrict__ b3,
    float* __restrict__ z)
{
    __shared__ __align__(16) char lds[36864];
    __shared__ float msum[C3];

    const int tid  = threadIdx.x;
    const int lane = tid & 63;
    const int wid  = tid >> 6;
    const int wm   = wid >> 1;       // wave row (M half)
    const int wn   = wid & 1;        // wave col (N half: 32 pts)
    const int g4   = lane >> 4;      // 0..3
    const int c16  = lane & 15;      // 0..15

    // ---- preload weight A-fragments into registers ----
    // A layout: lane holds A[row = lane&15][k = (lane>>4)*8 + j], j=0..7
    bf16x8 a1[4], a2[4][4], a3[2][4];
    {
        const int r1 = wm * 64 + c16;
        #pragma unroll
        for (int mf = 0; mf < 4; ++mf)
            a1[mf] = *(const bf16x8*)&w1p[(r1 + mf * 16) * 32 + g4 * 8];
        #pragma unroll
        for (int mf = 0; mf < 4; ++mf)
            #pragma unroll
            for (int kf = 0; kf < 4; ++kf)
                a2[mf][kf] = *(const bf16x8*)&w2b[(r1 + mf * 16) * C1 + kf * 32 + g4 * 8];
        const int r3 = wm * 32 + c16;
        #pragma unroll
        for (int mf = 0; mf < 2; ++mf)
            #pragma unroll
            for (int kf = 0; kf < 4; ++kf)
                a3[mf][kf] = *(const bf16x8*)&w3b[(r3 + mf * 16) * C2 + kf * 32 + g4 * 8];
    }

    const int pt   = tid & 63;       // staging: point owned by this thread
    const int half = tid >> 6;       // staging: channel quad half*4..half*4+3
    const int xoff = ldsoff(0, 4, pt, half >> 1) + (half & 1) * 8;

    for (int e = 0; e < EPB; ++e) {
        const int j     = blockIdx.x * EPB + e;
        const int start = bounds[j];
        const int cnt   = bounds[j + 1] - start;

        if (tid < C3) msum[tid] = 0.f;

        // ---- prologue: stage pass-0 X (loads -> cvt_pk -> one ds_write_b64) ----
        float xr[4];
        #pragma unroll
        for (int jj = 0; jj < 4; ++jj)
            xr[jj] = (pt < cnt) ? xa[(size_t)(half * 4 + jj) * L_PTS + start + pt] : 0.f;
        {
            union { unsigned u[2]; unsigned long long ll; } pk;
            pk.u[0] = cvtpk(xr[0], xr[1]);
            pk.u[1] = cvtpk(xr[2], xr[3]);
            *(unsigned long long*)(lds + xoff) = pk.ll;
        }
        __syncthreads();                       // (s) X + msum-zero visible; prev event done

        for (int p0 = 0; p0 < cnt; p0 += TPTS) {
            const bool more = (p0 + TPTS) < cnt;   // uniform per block

            // ---- issue next-pass X loads early (consumed after bar2) ----
            if (more) {
                const int p = p0 + TPTS + pt;
                #pragma unroll
                for (int jj = 0; jj < 4; ++jj)
                    xr[jj] = (p < cnt) ? xa[(size_t)(half * 4 + jj) * L_PTS + start + p] : 0.f;
            }

            // ---- layer 1: H1[128ch][64pt] = relu(W1p @ X), K=32 ----
            {
                f32x4 acc[4][2];
                #pragma unroll
                for (int mf = 0; mf < 4; ++mf) {
                    const f32x4 bb = *(const f32x4*)&b1[wm * 64 + mf * 16 + g4 * 4];
                    acc[mf][0] = bb; acc[mf][1] = bb;
                }
                bf16x8 bfrag[2];
                #pragma unroll
                for (int nf = 0; nf < 2; ++nf)
                    bfrag[nf] = *(const bf16x8*)(lds + ldsoff(0, 4, wn * 32 + nf * 16 + c16, g4));
                __builtin_amdgcn_s_setprio(1);
                #pragma unroll
                for (int nf = 0; nf < 2; ++nf)
                    #pragma unroll
                    for (int mf = 0; mf < 4; ++mf)
                        acc[mf][nf] = __builtin_amdgcn_mfma_f32_16x16x32_bf16(a1[mf], bfrag[nf], acc[mf][nf], 0, 0, 0);
                __builtin_amdgcn_s_setprio(0);
                #pragma unroll
                for (int mf = 0; mf < 4; ++mf)
                    #pragma unroll
                    for (int nf = 0; nf < 2; ++nf) {
                        const int c = wn * 32 + nf * 16 + c16;
                        const int sir = (wm * 64 + mf * 16) / 8 + (g4 >> 1);
                        *(unsigned long long*)(lds + ldsoff(4096, 16, c, sir) + (g4 & 1) * 8) = pack4relu(acc[mf][nf]);
                    }
            }
            __syncthreads();                   // bar1: H1 ready

            // ---- layer 2: H2 = relu(W2 @ H1), K=128 ----
            {
                f32x4 acc[4][2];
                #pragma unroll
                for (int mf = 0; mf < 4; ++mf) {
                    const f32x4 bb = *(const f32x4*)&b2[wm * 64 + mf * 16 + g4 * 4];
                    acc[mf][0] = bb; acc[mf][1] = bb;
                }
                #pragma unroll
                for (int nf = 0; nf < 2; ++nf) {
                    const int c = wn * 32 + nf * 16 + c16;
                    bf16x8 bk[4];
                    #pragma unroll
                    for (int kf = 0; kf < 4; ++kf)
                        bk[kf] = *(const bf16x8*)(lds + ldsoff(4096, 16, c, kf * 4 + g4));
                    __builtin_amdgcn_s_setprio(1);
                    #pragma unroll
                    for (int mf = 0; mf < 4; ++mf)
                        #pragma unroll
                        for (int kf = 0; kf < 4; ++kf)
                            acc[mf][nf] = __builtin_amdgcn_mfma_f32_16x16x32_bf16(a2[mf][kf], bk[kf], acc[mf][nf], 0, 0, 0);
                    __builtin_amdgcn_s_setprio(0);
                }
                #pragma unroll
                for (int mf = 0; mf < 4; ++mf)
                    #pragma unroll
                    for (int nf = 0; nf < 2; ++nf) {
                        const int c = wn * 32 + nf * 16 + c16;
                        const int sir = (wm * 64 + mf * 16) / 8 + (g4 >> 1);
                        *(unsigned long long*)(lds + ldsoff(20480, 16, c, sir) + (g4 & 1) * 8) = pack4relu(acc[mf][nf]);
                    }
            }
            __syncthreads();                   // bar2: H2 ready; L1's X reads long done

            // ---- write next-pass X (loads issued at loop top; latency hidden) ----
            if (more) {
                union { unsigned u[2]; unsigned long long ll; } pk;
                pk.u[0] = cvtpk(xr[0], xr[1]);
                pk.u[1] = cvtpk(xr[2], xr[3]);
                *(unsigned long long*)(lds + xoff) = pk.ll;
            }

            // ---- layer 3: H3 = relu(W3 @ H2), K=128, M=64; fused masked col-sum ----
            {
                f32x4 acc3[2][2];
                #pragma unroll
                for (int mf = 0; mf < 2; ++mf) {
                    const f32x4 bb = *(const f32x4*)&b3[wm * 32 + mf * 16 + g4 * 4];
                    acc3[mf][0] = bb; acc3[mf][1] = bb;
                }
                #pragma unroll
                for (int nf = 0; nf < 2; ++nf) {
                    const int c = wn * 32 + nf * 16 + c16;
                    bf16x8 bk[4];
                    #pragma unroll
                    for (int kf = 0; kf < 4; ++kf)
                        bk[kf] = *(const bf16x8*)(lds + ldsoff(20480, 16, c, kf * 4 + g4));
                    __builtin_amdgcn_s_setprio(1);
                    #pragma unroll
                    for (int mf = 0; mf < 2; ++mf)
                        #pragma unroll
                        for (int kf = 0; kf < 4; ++kf)
                            acc3[mf][nf] = __builtin_amdgcn_mfma_f32_16x16x32_bf16(a3[mf][kf], bk[kf], acc3[mf][nf], 0, 0, 0);
                    __builtin_amdgcn_s_setprio(0);
                }
                float s[2][4];
                #pragma unroll
                for (int mf = 0; mf < 2; ++mf)
                    #pragma unroll
                    for (int r = 0; r < 4; ++r) s[mf][r] = 0.f;
                #pragma unroll
                for (int nf = 0; nf < 2; ++nf) {
                    const int col = p0 + wn * 32 + nf * 16 + c16;
                    const bool valid = col < cnt;
                    #pragma unroll
                    for (int mf = 0; mf < 2; ++mf)
                        #pragma unroll
                        for (int r = 0; r < 4; ++r) {
                            const float v = fmaxf(acc3[mf][nf][r], 0.f);
                            if (valid) s[mf][r] += v;
                        }
                }
                // reduce across the 16 lanes of each g4 group (cols)
                #pragma unroll
                for (int mf = 0; mf < 2; ++mf)
                    #pragma unroll
                    for (int r = 0; r < 4; ++r) {
                        float v = s[mf][r];
                        #pragma unroll
                        for (int m = 1; m < 16; m <<= 1) v += __shfl_xor(v, m, 64);
                        s[mf][r] = v;
                    }
                if (c16 == 0) {
                    #pragma unroll
                    for (int mf = 0; mf < 2; ++mf)
                        #pragma unroll
                        for (int r = 0; r < 4; ++r)
                            atomicAdd(&msum[wm * 32 + mf * 16 + g4 * 4 + r], s[mf][r]);
                }
            }
            __syncthreads();                   // bar3: msum atomics + next-X visible
        }

        if (tid < C3) {
            const float inv = 1.f / (float)max(cnt, 1);
            z[(size_t)j * ZDIM + tid] = msum[tid] * inv;
        } else if (tid < ZDIM) {
            z[(size_t)j * ZDIM + tid] = xb[(size_t)j * DVEC + (tid - C3)];
        }
        // no barrier needed here: msum re-zero is by the same threads that read it,
        // and all other threads' next atomics are gated by >=2 barriers.
    }
}

// ---------------------------------------------------------------------------
// Kernel 2: y1 = z @ Wm1.T + bm1   [B,256], plus column sum/sumsq atomics
// ---------------------------------------------------------------------------
__global__ __launch_bounds__(256) void mlp1_kernel(
    const float* __restrict__ z, const float* __restrict__ Wm1, const float* __restrict__ bm1,
    float* __restrict__ y1, float* __restrict__ gsum, float* __restrict__ gsq)
{
    __shared__ float zs[16][ZDIM + 4];
    const int r0 = blockIdx.x * 16;
    const int tid = threadIdx.x;
    for (int i = tid; i < 16 * ZDIM; i += 256) {
        const int r = i / ZDIM, c = i - r * ZDIM;
        zs[r][c] = z[(size_t)(r0 + r) * ZDIM + c];
    }
    __syncthreads();
    const int o = tid;
    float acc[16];
    const float bb = bm1[o];
    #pragma unroll
    for (int r = 0; r < 16; ++r) acc[r] = bb;
    for (int c = 0; c < ZDIM; c += 4) {
        const float4 w = *(const float4*)&Wm1[o * ZDIM + c];
        #pragma unroll
        for (int r = 0; r < 16; ++r) {
            const float4 v = *(const float4*)&zs[r][c];
            acc[r] += w.x*v.x + w.y*v.y + w.z*v.z + w.w*v.w;
        }
    }
    float s = 0.f, sq = 0.f;
    #pragma unroll
    for (int r = 0; r < 16; ++r) {
        y1[(size_t)(r0 + r) * M1 + o] = acc[r];
        s += acc[r]; sq += acc[r] * acc[r];
    }
    atomicAdd(&gsum[o], s);
    atomicAdd(&gsq[o], sq);
}

// ---------------------------------------------------------------------------
// Kernel 3/5: finalize BN -> per-channel scale/shift
// ---------------------------------------------------------------------------
__global__ void bnfin_kernel(const float* __restrict__ gsum, const float* __restrict__ gsq,
                             const float* __restrict__ g, const float* __restrict__ be,
                             float* __restrict__ scale, float* __restrict__ shift, int n)
{
    const int o = blockIdx.x * blockDim.x + threadIdx.x;
    if (o >= n) return;
    const float mu  = gsum[o] * (1.f / B_EVENTS);
    const float var = gsq[o] * (1.f / B_EVENTS) - mu * mu;
    const float rs  = rsqrtf(var + BN_EPS);
    const float sc  = rs * g[o];
    scale[o] = sc;
    shift[o] = be[o] - mu * sc;
}

// ---------------------------------------------------------------------------
// Kernel 4: y2 = relu(bn(y1)) @ Wm2.T + bm2   [B,128], plus stats
// ---------------------------------------------------------------------------
__global__ __launch_bounds__(256) void mlp2_kernel(
    const float* __restrict__ y1, const float* __restrict__ scale1, const float* __restrict__ shift1,
    const float* __restrict__ Wm2, const float* __restrict__ bm2,
    float* __restrict__ y2, float* __restrict__ gsum, float* __restrict__ gsq)
{
    __shared__ float zs[16][M1 + 4];
    const int r0 = blockIdx.x * 16;
    const int tid = threadIdx.x;
    for (int i = tid; i < 16 * M1; i += 256) {
        const int r = i >> 8, c = i & (M1 - 1);
        const float v = y1[(size_t)(r0 + r) * M1 + c];
        zs[r][c] = fmaxf(v * scale1[c] + shift1[c], 0.f);
    }
    __syncthreads();
    const int o = tid & 127;
    const int h = tid >> 7;
    float acc[8];
    const float bb = bm2[o];
    #pragma unroll
    for (int r = 0; r < 8; ++r) acc[r] = bb;
    for (int c = 0; c < M1; c += 4) {
        const float4 w = *(const float4*)&Wm2[o * M1 + c];
        #pragma unroll
        for (int r = 0; r < 8; ++r) {
            const float4 v = *(const float4*)&zs[h * 8 + r][c];
            acc[r] += w.x*v.x + w.y*v.y + w.z*v.z + w.w*v.w;
        }
    }
    float s = 0.f, sq = 0.f;
    #pragma unroll
    for (int r = 0; r < 8; ++r) {
        y2[(size_t)(r0 + h * 8 + r) * M2 + o] = acc[r];
        s += acc[r]; sq += acc[r] * acc[r];
    }
    atomicAdd(&gsum[o], s);
    atomicAdd(&gsq[o], sq);
}

// ---------------------------------------------------------------------------
// Kernel 6: out = sigmoid(relu(bn(y2)) @ Wm3.T + bm3)   [B,1]
// ---------------------------------------------------------------------------
__global__ __launch_bounds__(256) void final_kernel(
    const float* __restrict__ y2, const float* __restrict__ scale2, const float* __restrict__ shift2,
    const float* __restrict__ Wm3, const float* __restrict__ bm3,
    float* __restrict__ out)
{
    const int tid = threadIdx.x;
    const int w = tid >> 6, l = tid & 63;
    const int r = blockIdx.x * 4 + w;
    const float e0 = fmaxf(y2[(size_t)r * M2 + l]      * scale2[l]      + shift2[l],      0.f);
    const float e1 = fmaxf(y2[(size_t)r * M2 + 64 + l] * scale2[64 + l] + shift2[64 + l], 0.f);
    float a = e0 * Wm3[l] + e1 * Wm3[64 + l];
    #pragma unroll
    for (int off = 32; off >= 1; off >>= 1) a += __shfl_down(a, off, 64);
    if (l == 0) out[r] = 1.f / (1.f + expf(-(a + bm3[0])));
}

// ---------------------------------------------------------------------------
extern "C" void kernel_launch(void* const* d_in, const int* in_sizes, int n_in,
                              void* d_out, int out_size, void* d_ws, size_t ws_size,
                              hipStream_t stream) {
    const float* xa  = (const float*)d_in[0];
    const float* xb  = (const float*)d_in[1];
    const int*   si  = (const int*)  d_in[2];
    const float* W1  = (const float*)d_in[3];
    const float* b1  = (const float*)d_in[4];
    const float* W2  = (const float*)d_in[5];
    const float* b2  = (const float*)d_in[6];
    const float* W3  = (const float*)d_in[7];
    const float* b3  = (const float*)d_in[8];
    const float* Wm1 = (const float*)d_in[9];
    const float* bm1 = (const float*)d_in[10];
    const float* g1  = (const float*)d_in[11];
    const float* be1 = (const float*)d_in[12];
    const float* Wm2 = (const float*)d_in[13];
    const float* bm2 = (const float*)d_in[14];
    const float* g2  = (const float*)d_in[15];
    const float* be2 = (const float*)d_in[16];
    const float* Wm3 = (const float*)d_in[17];
    const float* bm3 = (const float*)d_in[18];
    float* out = (float*)d_out;

    char* ws = (char*)d_ws;
    size_t off = 0;
    auto alloc = [&](size_t bytes) -> void* {
        void* p = ws + off;
        off = (off + bytes + 255) & ~(size_t)255;
        return p;
    };
    int*    bounds = (int*)   alloc((B_EVENTS + 1) * sizeof(int));
    float*  stats  = (float*) alloc(768 * sizeof(float));
    float*  z      = (float*) alloc((size_t)B_EVENTS * ZDIM * sizeof(float));
    float*  y1     = (float*) alloc((size_t)B_EVENTS * M1 * sizeof(float));
    float*  y2     = (float*) alloc((size_t)B_EVENTS * M2 * sizeof(float));
    float*  scale1 = (float*) alloc(M1 * sizeof(float));
    float*  shift1 = (float*) alloc(M1 * sizeof(float));
    float*  scale2 = (float*) alloc(M2 * sizeof(float));
    float*  shift2 = (float*) alloc(M2 * sizeof(float));
    ushort* w1p    = (ushort*)alloc(C1 * 32 * sizeof(ushort));
    ushort* w2b    = (ushort*)alloc(C2 * C1 * sizeof(ushort));
    ushort* w3b    = (ushort*)alloc(C3 * C2 * sizeof(ushort));
    float* gsum1 = stats;
    float* gsq1  = stats + 256;
    float* gsum2 = stats + 512;
    float* gsq2  = stats + 640;

    hipLaunchKernelGGL(scan_zero_kernel, dim3(1), dim3(1024), 0, stream, si, bounds, stats);
    hipLaunchKernelGGL(prep_kernel, dim3(16), dim3(256), 0, stream, W1, W2, W3, w1p, w2b, w3b);
    hipLaunchKernelGGL(phi_mfma_kernel, dim3(B_EVENTS / EPB), dim3(256), 0, stream,
                       xa, xb, bounds, w1p, w2b, w3b, b1, b2, b3, z);
    hipLaunchKernelGGL(mlp1_kernel, dim3(B_EVENTS / 16), dim3(256), 0, stream,
                       z, Wm1, bm1, y1, gsum1, gsq1);
    hipLaunchKernelGGL(bnfin_kernel, dim3(1), dim3(256), 0, stream,
                       gsum1, gsq1, g1, be1, scale1, shift1, M1);
    hipLaunchKernelGGL(mlp2_kernel, dim3(B_EVENTS / 16), dim3(256), 0, stream,
                       y1, scale1, shift1, Wm2, bm2, y2, gsum2, gsq2);
    hipLaunchKernelGGL(bnfin_kernel, dim3(1), dim3(128), 0, stream,
                       gsum2, gsq2, g2, be2, scale2, shift2, M2);
    hipLaunchKernelGGL(final_kernel, dim3(B_EVENTS / 4), dim3(256), 0, stream,
                       y2, scale2, shift2, Wm3, bm3, out);
}